// Round 1
// baseline (343.553 us; speedup 1.0000x reference)
//
#include <hip/hip_runtime.h>
#include <hip/hip_bf16.h>

#define D 128
#define SEQ 2048
#define NH 16
#define KVB 64
#define NTILE (SEQ / KVB)   // 32
#define QT 32               // q rows per warp
#define BLOCK_Q 128         // 4 warps per attention

typedef float f32x4  __attribute__((ext_vector_type(4)));
typedef float f32x16 __attribute__((ext_vector_type(16)));
typedef short bf16x8 __attribute__((ext_vector_type(8)));

struct Stg {
    char k1t[KVB * D * 2];   // [64][128] bf16, XOR-swizzled
    char k2t[KVB * D * 2];
    char vt [D * KVB * 2];   // V^T [128][64] bf16, XOR-swizzled
};
union LdsU {
    Stg   s;                 // 49152 B
    float oepi[BLOCK_Q * D]; // 65536 B
};

// pack two f32 -> bf16x2 (RNE)
__device__ __forceinline__ unsigned pk2(float a, float b){
    union { float f; unsigned u; } ua, ub;
    ua.f = a; ub.f = b;
    unsigned ra = (ua.u + 0x7fffu + ((ua.u >> 16) & 1u)) >> 16;
    unsigned rb = (ub.u + 0x7fffu + ((ub.u >> 16) & 1u)) >> 16;
    return (ra & 0xffffu) | (rb << 16);
}

__global__ __launch_bounds__(512, 2)
void diffattn(const float* __restrict__ q1, const float* __restrict__ k1,
              const float* __restrict__ v,  const float* __restrict__ q2,
              const float* __restrict__ k2, const float* __restrict__ ll,
              float* __restrict__ out)
{
    __shared__ LdsU lds;
    const int tid  = threadIdx.x;
    const int lane = tid & 63;
    const int wid  = tid >> 6;
    const int atn  = wid >> 2;      // 0: attn1 (warps 0-3), 1: attn2 (warps 4-7)
    const int wq   = wid & 3;       // 32-row slice within the 128-row block tile
    const int g    = lane >> 5;     // 32-lane half
    const int ql   = lane & 31;     // q row within warp tile (C/D col)
    const int h    = blockIdx.y;
    const int qb   = blockIdx.x;

    const size_t kvbase = (size_t)(h >> 2) * SEQ * D;   // GQA: head h -> kv head h/4

    // ---- Q fragments (B-operand layout: n=ql, k-slot (g,i) = d = dc*16+g*8+i) ----
    const float* Qbase = (atn ? q2 : q1)
        + ((size_t)h * SEQ + (size_t)qb * BLOCK_Q + wq * QT + ql) * D;
    const float qsc = 0.08838834764831845f * 1.4426950408889634f; // rsqrt(128)*log2(e)
    bf16x8 qf[8];
    #pragma unroll
    for (int dc = 0; dc < 8; ++dc){
        const float* p = Qbase + dc*16 + g*8;
        f32x4 a = *(const f32x4*)(p);
        f32x4 b = *(const f32x4*)(p + 4);
        union { bf16x8 v; unsigned u[4]; } u;
        u.u[0] = pk2(a[0]*qsc, a[1]*qsc);
        u.u[1] = pk2(a[2]*qsc, a[3]*qsc);
        u.u[2] = pk2(b[0]*qsc, b[1]*qsc);
        u.u[3] = pk2(b[2]*qsc, b[3]*qsc);
        qf[dc] = u.v;
    }

    f32x16 ot[4];                      // O^T accum: lane holds O[q=ql][d=db*32+(e&3)+8*(e>>2)+4g]
    #pragma unroll
    for (int i = 0; i < 4; ++i){
        #pragma unroll
        for (int e = 0; e < 16; ++e) ot[i][e] = 0.f;
    }
    float mrun = -1e30f, lrun = 0.f;

    const char* kt = atn ? lds.s.k2t : lds.s.k1t;

    const int srow = tid >> 3;         // K staging: row 0..63
    const int scol = (tid & 7) * 4;    // f32 col base
    const int vd   = tid & 127;        // V^T staging: d row
    const int vkg  = tid >> 7;         // key group 0..3 (16 keys each)

    for (int t = 0; t < NTILE; ++t){
        // ---- stage K1,K2: [64][128] f32 -> bf16 swizzled ----
        {
            const size_t rowoff = kvbase + (size_t)(t*KVB + srow) * D + scol;
            const int swz = (srow & 7) << 4;
            #pragma unroll
            for (int j = 0; j < 4; ++j){
                f32x4 x1 = *(const f32x4*)(k1 + rowoff + j*32);
                f32x4 x2 = *(const f32x4*)(k2 + rowoff + j*32);
                uint2 w1, w2;
                w1.x = pk2(x1[0], x1[1]); w1.y = pk2(x1[2], x1[3]);
                w2.x = pk2(x2[0], x2[1]); w2.y = pk2(x2[2], x2[3]);
                int off = (srow*256 + (scol + j*32)*2) ^ swz;
                *(uint2*)(lds.s.k1t + off) = w1;
                *(uint2*)(lds.s.k2t + off) = w2;
            }
        }
        // ---- stage V^T: [128][64] bf16 swizzled (coalesced strided reads) ----
        {
            const float* vp = v + kvbase + (size_t)(t*KVB + vkg*16) * D + vd;
            float vv[16];
            #pragma unroll
            for (int j = 0; j < 16; ++j) vv[j] = vp[(size_t)j * D];
            uint4 wa, wb;
            wa.x = pk2(vv[0], vv[1]);  wa.y = pk2(vv[2], vv[3]);
            wa.z = pk2(vv[4], vv[5]);  wa.w = pk2(vv[6], vv[7]);
            wb.x = pk2(vv[8], vv[9]);  wb.y = pk2(vv[10],vv[11]);
            wb.z = pk2(vv[12],vv[13]); wb.w = pk2(vv[14],vv[15]);
            const int swz = (vd & 7) << 4;
            const int base = vd*128 + vkg*32;
            *(uint4*)(lds.s.vt + ( base        ^ swz)) = wa;
            *(uint4*)(lds.s.vt + ((base + 16)  ^ swz)) = wb;
        }
        __syncthreads();

        // ---- swapped QK^T: ST[key][q] = K·Q^T ----
        f32x16 st[2];
        #pragma unroll
        for (int kb = 0; kb < 2; ++kb){
            f32x16 acc;
            #pragma unroll
            for (int e = 0; e < 16; ++e) acc[e] = 0.f;
            const int krow = kb*32 + ql;
            const int kswz = (krow & 7) << 4;
            #pragma unroll
            for (int dc = 0; dc < 8; ++dc){
                int off = (krow*256 + dc*32 + g*16) ^ kswz;
                bf16x8 kf = *(const bf16x8*)(kt + off);
                acc = __builtin_amdgcn_mfma_f32_32x32x16_bf16(kf, qf[dc], acc, 0, 0, 0);
            }
            st[kb] = acc;
        }

        // ---- online softmax (exp2 domain); lane covers q=ql, keys split across g ----
        float tmax = -1e30f;
        #pragma unroll
        for (int kb = 0; kb < 2; ++kb){
            #pragma unroll
            for (int e = 0; e < 16; ++e) tmax = fmaxf(tmax, st[kb][e]);
        }
        tmax = fmaxf(tmax, __shfl_xor(tmax, 32));
        const float mnew = fmaxf(mrun, tmax);
        const float corr = exp2f(mrun - mnew);
        float p[2][16];
        float ps = 0.f;
        #pragma unroll
        for (int kb = 0; kb < 2; ++kb){
            #pragma unroll
            for (int e = 0; e < 16; ++e){
                float pe = exp2f(st[kb][e] - mnew);
                p[kb][e] = pe; ps += pe;
            }
        }
        ps += __shfl_xor(ps, 32);
        lrun = lrun * corr + ps;
        mrun = mnew;
        #pragma unroll
        for (int i = 0; i < 4; ++i) ot[i] = ot[i] * corr;

        // ---- repack P -> bf16 B-frag (keys kc*16 + g*8 + i per lane) ----
        // source key = kb*32 + (reg&3) + 8*(reg>>2) + 4*g ; h = 2*(kc&1)+g_dst, b=g_src
        unsigned W[2][4][2];
        #pragma unroll
        for (int kb = 0; kb < 2; ++kb){
            #pragma unroll
            for (int hh = 0; hh < 4; ++hh){
                #pragma unroll
                for (int jj = 0; jj < 2; ++jj)
                    W[kb][hh][jj] = pk2(p[kb][4*hh + 2*jj], p[kb][4*hh + 2*jj + 1]);
            }
        }
        bf16x8 pb[4];
        #pragma unroll
        for (int kc = 0; kc < 4; ++kc){
            const int kb = kc >> 1, b0 = 2*(kc & 1);
            union { bf16x8 v; unsigned u[4]; } pu;
            #pragma unroll
            for (int j = 0; j < 4; ++j){
                const int gsrc = j >> 1, jj = j & 1;
                unsigned loc = W[kb][b0 + g][jj];
                unsigned rem = (unsigned)__shfl_xor((int)W[kb][b0 + (g ^ 1)][jj], 32);
                pu.u[j] = (gsrc == g) ? loc : rem;
            }
            pb[kc] = pu.v;
        }

        // ---- PV: O^T += V^T · P^T ----
        #pragma unroll
        for (int db = 0; db < 4; ++db){
            const int drow = db*32 + ql;
            const int vswz = (drow & 7) << 4;
            #pragma unroll
            for (int kc = 0; kc < 4; ++kc){
                int off = (drow*128 + kc*32 + g*16) ^ vswz;
                bf16x8 vf = *(const bf16x8*)(lds.s.vt + off);
                ot[db] = __builtin_amdgcn_mfma_f32_32x32x16_bf16(vf, pb[kc], ot[db], 0, 0, 0);
            }
        }
        __syncthreads();
    }

    // ---- epilogue: out = O1/l1 - exp(lambda_log)*O2/l2, combined via LDS ----
    const float lam = expf(ll[0]);
    const float inv = 1.f / lrun;
    const int rowl = wq*32 + ql;
    const int eswz = (rowl & 7) << 2;

    if (atn == 1){
        const float s = lam * inv;
        #pragma unroll
        for (int db = 0; db < 4; ++db){
            #pragma unroll
            for (int e = 0; e < 16; ++e){
                int d = db*32 + (e & 3) + 8*(e >> 2) + 4*g;
                lds.oepi[rowl*128 + (d ^ eswz)] = ot[db][e] * s;
            }
        }
    }
    __syncthreads();
    if (atn == 0){
        #pragma unroll
        for (int db = 0; db < 4; ++db){
            #pragma unroll
            for (int e = 0; e < 16; ++e){
                int d = db*32 + (e & 3) + 8*(e >> 2) + 4*g;
                int idx = rowl*128 + (d ^ eswz);
                lds.oepi[idx] = ot[db][e] * inv - lds.oepi[idx];
            }
        }
    }
    __syncthreads();

    const size_t obase = ((size_t)h * SEQ + (size_t)qb * BLOCK_Q) * D;
    #pragma unroll
    for (int r2 = 0; r2 < 2; ++r2){
        int row = (tid >> 3) + r2*64;
        int sw  = (row & 7) << 2;
        #pragma unroll
        for (int j = 0; j < 4; ++j){
            int c = j*32 + (tid & 7)*4;
            f32x4 val = *(const f32x4*)&lds.oepi[row*128 + (c ^ sw)];
            *(f32x4*)(out + obase + (size_t)row*D + c) = val;
        }
    }
}

extern "C" void kernel_launch(void* const* d_in, const int* in_sizes, int n_in,
                              void* d_out, int out_size, void* d_ws, size_t ws_size,
                              hipStream_t stream)
{
    (void)in_sizes; (void)n_in; (void)out_size; (void)d_ws; (void)ws_size;
    const float* q1 = (const float*)d_in[0];
    const float* k1 = (const float*)d_in[1];
    const float* v  = (const float*)d_in[2];
    const float* q2 = (const float*)d_in[3];
    const float* k2 = (const float*)d_in[4];
    const float* ll = (const float*)d_in[5];
    dim3 grid(SEQ / BLOCK_Q, NH, 1);   // (16, 16)
    diffattn<<<grid, 512, 0, stream>>>(q1, k1, v, q2, k2, ll, (float*)d_out);
}

// Round 2
// 183.671 us; speedup vs baseline: 1.8705x; 1.8705x over previous
//
#include <hip/hip_runtime.h>
#include <hip/hip_bf16.h>
#include <stdint.h>

#define D 128
#define SEQ 2048
#define NH 16
#define KVB 64
#define NTILE 32
#define BLOCK_Q 128

typedef float f32x4  __attribute__((ext_vector_type(4)));
typedef float f32x16 __attribute__((ext_vector_type(16)));
typedef short bf16x8 __attribute__((ext_vector_type(8)));

__device__ __forceinline__ unsigned cvtpk(float lo, float hi){
    unsigned r;
    asm("v_cvt_pk_bf16_f32 %0, %1, %2" : "=v"(r) : "v"(lo), "v"(hi));
    return r;
}

// ---------------- prep: f32 -> bf16, pre-swizzled LDS tile images in ws ----------
// wsK1 [0,2MB):   16B chunk addr = grow*256 + c16*16, content = K1[grow][(c16^(grow&7))*8 ..+8]
// wsK2 [2MB,4MB): same for k2
// wsV  [4MB,6MB): chunk addr = (kvt*1024 + d*8 + c16)*16, content = V[kvt*64 + (c16^(d&7))*8 + j][d]
__global__ __launch_bounds__(256) void prep(const float* __restrict__ k1,
                                            const float* __restrict__ k2,
                                            const float* __restrict__ v,
                                            char* __restrict__ ws)
{
    int cid = blockIdx.x * 256 + threadIdx.x;
    if (cid < 262144){
        const float* src = (cid & 131072) ? k2 : k1;
        int r    = cid & 131071;
        int grow = r >> 4;                 // kvt*64 + row
        int c16  = r & 15;
        const float* p = src + (size_t)grow * D + ((c16 ^ (grow & 7)) << 3);
        f32x4 a = *(const f32x4*)p;
        f32x4 b = *(const f32x4*)(p + 4);
        uint4 w;
        w.x = cvtpk(a[0], a[1]); w.y = cvtpk(a[2], a[3]);
        w.z = cvtpk(b[0], b[1]); w.w = cvtpk(b[2], b[3]);
        *(uint4*)(ws + (size_t)cid * 16) = w;
    } else {
        int r   = cid - 262144;            // 0..131071
        int d   = (r >> 3) & 127;
        int c16 = r & 7;
        int gk  = ((r >> 10) << 6) + ((c16 ^ (d & 7)) << 3);  // kvt*64 + srck
        const float* p = v + (size_t)gk * D + d;
        uint4 w;
        w.x = cvtpk(p[0*D], p[1*D]);
        w.y = cvtpk(p[2*D], p[3*D]);
        w.z = cvtpk(p[4*D], p[5*D]);
        w.w = cvtpk(p[6*D], p[7*D]);
        *(uint4*)(ws + 4194304 + (size_t)r * 16) = w;
    }
}

// ---------------- main kernel ----------------
struct Buf { char k1[16384]; char k2[16384]; char vt[16384]; };
union LdsU { Buf buf[2]; float oepi[BLOCK_Q * D]; };   // 96 KiB

__global__ __launch_bounds__(512, 2)
void diffattn(const float* __restrict__ q1, const float* __restrict__ q2,
              const float* __restrict__ ll, const char* __restrict__ ws,
              float* __restrict__ out)
{
    __shared__ LdsU lds;
    const int tid  = threadIdx.x;
    const int lane = tid & 63;
    const int wid  = tid >> 6;
    const int atn  = wid >> 2;      // warps 0-3: attn1, 4-7: attn2
    const int wq   = wid & 3;
    const int g    = lane >> 5;
    const int ql   = lane & 31;

    // XCD-chunked swizzle: each XCD gets 32 consecutive logical blocks = 2 heads = 1 kv-head
    const int bid  = blockIdx.x;
    const int sbid = (bid & 7) * 32 + (bid >> 3);
    const int qb   = sbid & 15;
    const int h    = sbid >> 4;
    const int kvh  = h >> 2;

    auto stage = [&](int b, int t){
        const char* base = ws + ((size_t)(kvh * NTILE + t) << 14) + (lane << 4);
        char* lb = (char*)&lds.buf[b];
        #pragma unroll
        for (int j = 0; j < 6; ++j){
            int ci  = wid * 6 + j;           // 0..47: 16 K1 + 16 K2 + 16 V chunks of 1KB
            int mat = ci >> 4, sub = ci & 15;
            __builtin_amdgcn_global_load_lds(
                (const __attribute__((address_space(1))) void*)(base + (size_t)mat * 2097152 + (sub << 10)),
                (__attribute__((address_space(3))) void*)(lb + mat * 16384 + (sub << 10)),
                16, 0, 0);
        }
    };
    stage(0, 0);

    // ---- Q fragments (B-operand: n=ql, k-slot (g,i) -> d = dc*16+g*8+i) ----
    const float* Qbase = (atn ? q2 : q1)
        + ((size_t)h * SEQ + (size_t)qb * BLOCK_Q + wq * 32 + ql) * D;
    const float qsc = 0.08838834764831845f * 1.4426950408889634f; // rsqrt(128)*log2(e)
    bf16x8 qf[8];
    #pragma unroll
    for (int dc = 0; dc < 8; ++dc){
        const float* p = Qbase + dc * 16 + g * 8;
        f32x4 a = *(const f32x4*)(p);
        f32x4 b = *(const f32x4*)(p + 4);
        union { bf16x8 v; unsigned u[4]; } u;
        u.u[0] = cvtpk(a[0] * qsc, a[1] * qsc);
        u.u[1] = cvtpk(a[2] * qsc, a[3] * qsc);
        u.u[2] = cvtpk(b[0] * qsc, b[1] * qsc);
        u.u[3] = cvtpk(b[2] * qsc, b[3] * qsc);
        qf[dc] = u.v;
    }

    f32x16 ot[4];
    #pragma unroll
    for (int i = 0; i < 4; ++i){
        #pragma unroll
        for (int e = 0; e < 16; ++e) ot[i][e] = 0.f;
    }
    float mrun = -1e30f, lrun = 0.f;

    __syncthreads();

    for (int t = 0; t < NTILE; ++t){
        const int cur = t & 1;
        if (t + 1 < NTILE) stage(cur ^ 1, t + 1);   // async prefetch overlaps compute

        const char* kt = atn ? lds.buf[cur].k2 : lds.buf[cur].k1;
        const char* vt = lds.buf[cur].vt;

        // ---- swapped QK^T ----
        f32x16 st[2];
        __builtin_amdgcn_s_setprio(1);
        #pragma unroll
        for (int kb = 0; kb < 2; ++kb){
            f32x16 acc;
            #pragma unroll
            for (int e = 0; e < 16; ++e) acc[e] = 0.f;
            const int krow = kb * 32 + ql;
            const int kswz = (krow & 7) << 4;
            #pragma unroll
            for (int dc = 0; dc < 8; ++dc){
                bf16x8 kf = *(const bf16x8*)(kt + ((krow * 256 + dc * 32 + g * 16) ^ kswz));
                acc = __builtin_amdgcn_mfma_f32_32x32x16_bf16(kf, qf[dc], acc, 0, 0, 0);
            }
            st[kb] = acc;
        }
        __builtin_amdgcn_s_setprio(0);

        // ---- online softmax (exp2 domain), defer-max THR=8 ----
        float tmax = -1e30f;
        #pragma unroll
        for (int kb = 0; kb < 2; ++kb){
            #pragma unroll
            for (int e = 0; e < 16; ++e) tmax = fmaxf(tmax, st[kb][e]);
        }
        tmax = fmaxf(tmax, __shfl_xor(tmax, 32));
        if (!__all(tmax <= mrun + 8.f)){
            float mnew = fmaxf(mrun, tmax);
            float corr = exp2f(mrun - mnew);
            lrun *= corr;
            #pragma unroll
            for (int i = 0; i < 4; ++i) ot[i] = ot[i] * corr;
            mrun = mnew;
        }
        float p[2][16];
        float ps = 0.f;
        #pragma unroll
        for (int kb = 0; kb < 2; ++kb){
            #pragma unroll
            for (int e = 0; e < 16; ++e){
                float pe = exp2f(st[kb][e] - mrun);
                p[kb][e] = pe; ps += pe;
            }
        }
        ps += __shfl_xor(ps, 32);
        lrun += ps;

        // ---- repack P -> bf16 B-frags ----
        unsigned W[2][4][2];
        #pragma unroll
        for (int kb = 0; kb < 2; ++kb){
            #pragma unroll
            for (int hh = 0; hh < 4; ++hh){
                #pragma unroll
                for (int jj = 0; jj < 2; ++jj)
                    W[kb][hh][jj] = cvtpk(p[kb][4*hh + 2*jj], p[kb][4*hh + 2*jj + 1]);
            }
        }
        bf16x8 pb[4];
        #pragma unroll
        for (int kc = 0; kc < 4; ++kc){
            const int kb = kc >> 1, b0 = 2 * (kc & 1);
            union { bf16x8 v; unsigned u[4]; } pu;
            #pragma unroll
            for (int j = 0; j < 4; ++j){
                const int gsrc = j >> 1, jj = j & 1;
                unsigned wlo = W[kb][b0][jj];       // static indices only (rule #20)
                unsigned whi = W[kb][b0 + 1][jj];
                unsigned loc = g ? whi : wlo;
                unsigned oth = g ? wlo : whi;
                unsigned rem = (unsigned)__shfl_xor((int)oth, 32);
                pu.u[j] = (gsrc == g) ? loc : rem;
            }
            pb[kc] = pu.v;
        }

        // ---- PV: O^T += V^T · P^T ----
        __builtin_amdgcn_s_setprio(1);
        #pragma unroll
        for (int db = 0; db < 4; ++db){
            const int drow = db * 32 + ql;
            const int vswz = (drow & 7) << 4;
            #pragma unroll
            for (int kc = 0; kc < 4; ++kc){
                bf16x8 vf = *(const bf16x8*)(vt + ((drow * 128 + kc * 32 + g * 16) ^ vswz));
                ot[db] = __builtin_amdgcn_mfma_f32_32x32x16_bf16(vf, pb[kc], ot[db], 0, 0, 0);
            }
        }
        __builtin_amdgcn_s_setprio(0);
        __syncthreads();
    }

    // ---- epilogue: combine attn1 - lam*attn2 via LDS, coalesced store ----
    const float lam = expf(ll[0]);
    const float inv = 1.f / lrun;
    const int rowl = wq * 32 + ql;
    const int eswz = (rowl & 7) << 2;

    if (atn == 1){
        const float s = -lam * inv;
        #pragma unroll
        for (int db = 0; db < 4; ++db){
            #pragma unroll
            for (int e = 0; e < 16; ++e){
                int d = db * 32 + (e & 3) + 8 * (e >> 2) + 4 * g;
                lds.oepi[rowl * 128 + (d ^ eswz)] = ot[db][e] * s;
            }
        }
    }
    __syncthreads();
    if (atn == 0){
        #pragma unroll
        for (int db = 0; db < 4; ++db){
            #pragma unroll
            for (int e = 0; e < 16; ++e){
                int d = db * 32 + (e & 3) + 8 * (e >> 2) + 4 * g;
                int idx = rowl * 128 + (d ^ eswz);
                lds.oepi[idx] = ot[db][e] * inv + lds.oepi[idx];
            }
        }
    }
    __syncthreads();

    const size_t obase = ((size_t)h * SEQ + (size_t)qb * BLOCK_Q) * D;
    const int row = tid >> 2;
    const int q4  = tid & 3;
    const int sw  = (row & 7) << 2;
    #pragma unroll
    for (int j = 0; j < 8; ++j){
        int c = q4 * 32 + j * 4;
        f32x4 val = *(const f32x4*)&lds.oepi[row * 128 + (c ^ sw)];
        *(f32x4*)(out + obase + (size_t)row * D + c) = val;
    }
}

extern "C" void kernel_launch(void* const* d_in, const int* in_sizes, int n_in,
                              void* d_out, int out_size, void* d_ws, size_t ws_size,
                              hipStream_t stream)
{
    (void)in_sizes; (void)n_in; (void)out_size; (void)ws_size;
    const float* q1 = (const float*)d_in[0];
    const float* k1 = (const float*)d_in[1];
    const float* v  = (const float*)d_in[2];
    const float* q2 = (const float*)d_in[3];
    const float* k2 = (const float*)d_in[4];
    const float* ll = (const float*)d_in[5];
    prep<<<1536, 256, 0, stream>>>(k1, k2, v, (char*)d_ws);
    diffattn<<<256, 512, 0, stream>>>(q1, q2, ll, (const char*)d_ws, (float*)d_out);
}